// Round 16
// baseline (92.266 us; speedup 1.0000x reference)
//
#include <hip/hip_runtime.h>

#define NRAYS 16384
#define SSTEPS 1024
#define GRES 128
#define NSAMP ((size_t)NRAYS * (size_t)SSTEPS)   // 16777216

// One 64-lane wave per ray; lane owns 16 consecutive samples (whole ray in
// one chunk: single wave-scan, no carried-tau serialization). Coalesced
// float4 stores, 4 KB contiguous per wave per output.
extern "C" __global__ __launch_bounds__(256) void NeRFAccSampler_55791625175295_kernel(
    const float* __restrict__ rays_o,
    const float* __restrict__ rays_d,
    const float* __restrict__ jitter,
    const float* __restrict__ Wd,
    const float* __restrict__ bd,
    const unsigned char* __restrict__ binaries,
    float* __restrict__ out)
{
#pragma clang fp contract(off)
    const int tid  = blockIdx.x * 256 + (int)threadIdx.x;
    const int ray  = tid >> 6;
    const int lane = (int)threadIdx.x & 63;
    if (ray >= NRAYS) return;

    const float STEP = (float)(2.0 * 1.7320508075688772 / 1024.0);
    const float KEEP_THR = 9.2103405f;   // fl32(-ln 1e-4); excl < THR <=> T > 1e-4

    const float ox = rays_o[3 * ray + 0], oy = rays_o[3 * ray + 1], oz = rays_o[3 * ray + 2];
    const float dx = rays_d[3 * ray + 0], dy = rays_d[3 * ray + 1], dz = rays_d[3 * ray + 2];
    const float jit = jitter[ray];
    const float w0 = Wd[0], w1 = Wd[1], w2 = Wd[2], bb = bd[0];

    // slab test vs [-1,1]^3 (numpy-identical f32 rounding; inputs finite)
    const float ivx = 1.0f / dx, ivy = 1.0f / dy, ivz = 1.0f / dz;
    const float t0x = (-1.0f - ox) * ivx;
    const float t1x = ( 1.0f - ox) * ivx;
    const float t0y = (-1.0f - oy) * ivy;
    const float t1y = ( 1.0f - oy) * ivy;
    const float t0z = (-1.0f - oz) * ivz;
    const float t1z = ( 1.0f - oz) * ivz;
    const float tnx = t0x < t1x ? t0x : t1x, tXx = t0x > t1x ? t0x : t1x;
    const float tny = t0y < t1y ? t0y : t1y, tXy = t0y > t1y ? t0y : t1y;
    const float tnz = t0z < t1z ? t0z : t1z, tXz = t0z > t1z ? t0z : t1z;
    float t_near = tnx;
    if (tny > t_near) t_near = tny;
    if (tnz > t_near) t_near = tnz;
    if (t_near < 0.0f) t_near = 0.0f;
    float t_far = tXx;
    if (tXy < t_far) t_far = tXy;
    if (tXz < t_far) t_far = tXz;
    const bool hit = t_near < t_far;

    const int   s0 = lane << 4;               // this lane's first sample
    const float t_lane0 = t_near + jit * STEP; // t_start(i) = t_lane0 + i*STEP (recompute form)

    float loc[16];
    unsigned int vmask = 0;
    float sum = 0.0f;

    #pragma unroll
    for (int k = 0; k < 16; ++k) {
        const float fi = (float)(s0 + k);
        const float t_start = t_near + (fi + jit) * STEP;
        const float t_end   = t_start + STEP;
        const float mid     = (t_start + t_end) * 0.5f;
        const float px = ox + dx * mid;
        const float py = oy + dy * mid;
        const float pz = oz + dz * mid;

        // cell = clip(floor((p+1)*64), 0, 127); clamp-then-trunc, NaN-safe
        float vx = (px + 1.0f) * 64.0f;
        float vy = (py + 1.0f) * 64.0f;
        float vz = (pz + 1.0f) * 64.0f;
        if (!(vx > 0.0f)) vx = 0.0f;
        if (vx > 127.0f)  vx = 127.0f;
        if (!(vy > 0.0f)) vy = 0.0f;
        if (vy > 127.0f)  vy = 127.0f;
        if (!(vz > 0.0f)) vz = 0.0f;
        if (vz > 127.0f)  vz = 127.0f;
        const int flat = (((int)vx * GRES) + (int)vy) * GRES + (int)vz;
        const bool occ = binaries[flat] != 0;

        const bool valid = occ && (t_end < t_far) && hit;

        float sig = ((px * w0 + py * w1) + pz * w2) + bb;
        if (sig < 0.0f) sig = 0.0f;
        const float sstep = (valid ? sig : 0.0f) * STEP;

        vmask |= (valid ? 1u : 0u) << k;
        loc[k] = sum;              // lane-local exclusive prefix
        sum    = sum + sstep;
    }

    // single wave-level inclusive scan of lane totals (6 shuffle steps)
    float run = sum;
    #pragma unroll
    for (int d = 1; d < 64; d <<= 1) {
        const float y = __shfl_up(run, d, 64);
        if (lane >= d) run += y;
    }
    const float exbase = run - sum;   // exclusive prefix entering this lane

    const size_t base  = (size_t)ray * (size_t)SSTEPS + (size_t)s0;
    const float  ray_f = (float)ray;
    const float4 o0v   = make_float4(ray_f, ray_f, ray_f, ray_f);

    #pragma unroll
    for (int g = 0; g < 4; ++g) {
        float a1[4], a2[4], a3[4];
        #pragma unroll
        for (int j = 0; j < 4; ++j) {
            const int   k       = (g << 2) + j;
            const float t_start = t_lane0 + (float)(s0 + k) * STEP;   // cheap recompute
            // NOTE: recompute uses (fi*STEP + t_lane0) vs original (fi+jit)*STEP+t_near;
            // rounding may differ 1 ulp -> recompute exactly instead:
            const float ts = t_near + ((float)(s0 + k) + jit) * STEP;
            const float te = ts + STEP;
            const bool keep = ((vmask >> k) & 1u) && ((exbase + loc[k]) < KEEP_THR);
            a1[j] = keep ? ts : 0.0f;
            a2[j] = keep ? te : 0.0f;
            a3[j] = keep ? 1.0f : 0.0f;
            (void)t_start;
        }
        const size_t o = base + (size_t)(g << 2);
        *reinterpret_cast<float4*>(&out[o])             = o0v;
        *reinterpret_cast<float4*>(&out[NSAMP + o])     = make_float4(a1[0], a1[1], a1[2], a1[3]);
        *reinterpret_cast<float4*>(&out[2 * NSAMP + o]) = make_float4(a2[0], a2[1], a2[2], a2[3]);
        *reinterpret_cast<float4*>(&out[3 * NSAMP + o]) = make_float4(a3[0], a3[1], a3[2], a3[3]);
    }
}

extern "C" void kernel_launch(void* const* d_in, const int* in_sizes, int n_in,
                              void* d_out, int out_size, void* d_ws, size_t ws_size,
                              hipStream_t stream) {
    const float* rays_o           = (const float*)d_in[0];
    const float* rays_d           = (const float*)d_in[1];
    const float* jitter           = (const float*)d_in[2];
    const float* Wd               = (const float*)d_in[3];
    const float* bd               = (const float*)d_in[4];
    const unsigned char* binaries = (const unsigned char*)d_in[5];
    float* out                    = (float*)d_out;

    // 4 waves (4 rays) per 256-thread block; 4096 blocks = 16384 waves.
    NeRFAccSampler_55791625175295_kernel<<<NRAYS / 4, 256, 0, stream>>>(
        rays_o, rays_d, jitter, Wd, bd, binaries, out);
}

// Round 17
// 51.409 us; speedup vs baseline: 1.7947x; 1.7947x over previous
//
#include <hip/hip_runtime.h>

#define NRAYS 16384
#define SSTEPS 1024
#define GRES 128
#define NSAMP ((size_t)NRAYS * (size_t)SSTEPS)   // 16777216

// One 64-lane wave per ray. R15 layout (lane owns 4 consecutive samples per
// 256-sample chunk -> every float4 store is a contiguous 1KB wave burst),
// but with all 4 wave-scans hoisted out of the chunk loop and batched so
// their shuffle latency overlaps (no carried-tau serialization between
// compute iterations). Chunk carry = 3 scalar adds, same fp order as R15.
extern "C" __global__ __launch_bounds__(256) void NeRFAccSampler_55791625175295_kernel(
    const float* __restrict__ rays_o,
    const float* __restrict__ rays_d,
    const float* __restrict__ jitter,
    const float* __restrict__ Wd,
    const float* __restrict__ bd,
    const unsigned char* __restrict__ binaries,
    float* __restrict__ out)
{
#pragma clang fp contract(off)
    const int tid  = blockIdx.x * 256 + (int)threadIdx.x;
    const int ray  = tid >> 6;
    const int lane = (int)threadIdx.x & 63;
    if (ray >= NRAYS) return;

    const float STEP = (float)(2.0 * 1.7320508075688772 / 1024.0);
    const float KEEP_THR = 9.2103405f;   // fl32(-ln 1e-4); excl < THR <=> T > 1e-4

    const float ox = rays_o[3 * ray + 0], oy = rays_o[3 * ray + 1], oz = rays_o[3 * ray + 2];
    const float dx = rays_d[3 * ray + 0], dy = rays_d[3 * ray + 1], dz = rays_d[3 * ray + 2];
    const float jit = jitter[ray];
    const float w0 = Wd[0], w1 = Wd[1], w2 = Wd[2], bb = bd[0];

    // slab test vs [-1,1]^3 (numpy-identical f32 rounding; inputs finite)
    const float ivx = 1.0f / dx, ivy = 1.0f / dy, ivz = 1.0f / dz;
    const float t0x = (-1.0f - ox) * ivx;
    const float t1x = ( 1.0f - ox) * ivx;
    const float t0y = (-1.0f - oy) * ivy;
    const float t1y = ( 1.0f - oy) * ivy;
    const float t0z = (-1.0f - oz) * ivz;
    const float t1z = ( 1.0f - oz) * ivz;
    const float tnx = t0x < t1x ? t0x : t1x, tXx = t0x > t1x ? t0x : t1x;
    const float tny = t0y < t1y ? t0y : t1y, tXy = t0y > t1y ? t0y : t1y;
    const float tnz = t0z < t1z ? t0z : t1z, tXz = t0z > t1z ? t0z : t1z;
    float t_near = tnx;
    if (tny > t_near) t_near = tny;
    if (tnz > t_near) t_near = tnz;
    if (t_near < 0.0f) t_near = 0.0f;
    float t_far = tXx;
    if (tXy < t_far) t_far = tXy;
    if (tXz < t_far) t_far = tXz;
    const bool hit = t_near < t_far;

    // ---- Pass 1: per-chunk lane-local prefixes, totals, validity ----
    float loc[4][4];          // [chunk][k] exclusive local prefix
    float lsum[4];            // [chunk] lane total
    unsigned int vmask = 0;   // 16 validity bits: chunk*4 + k

    #pragma unroll
    for (int c = 0; c < 4; ++c) {
        const int s0 = (c << 8) + (lane << 2);
        float sum = 0.0f;
        #pragma unroll
        for (int k = 0; k < 4; ++k) {
            const float fi = (float)(s0 + k);
            const float t_start = t_near + (fi + jit) * STEP;
            const float t_end   = t_start + STEP;
            const float mid     = (t_start + t_end) * 0.5f;
            const float px = ox + dx * mid;
            const float py = oy + dy * mid;
            const float pz = oz + dz * mid;

            float vx = (px + 1.0f) * 64.0f;
            float vy = (py + 1.0f) * 64.0f;
            float vz = (pz + 1.0f) * 64.0f;
            if (!(vx > 0.0f)) vx = 0.0f;
            if (vx > 127.0f)  vx = 127.0f;
            if (!(vy > 0.0f)) vy = 0.0f;
            if (vy > 127.0f)  vy = 127.0f;
            if (!(vz > 0.0f)) vz = 0.0f;
            if (vz > 127.0f)  vz = 127.0f;
            const int flat = (((int)vx * GRES) + (int)vy) * GRES + (int)vz;
            const bool occ = binaries[flat] != 0;

            const bool valid = occ && (t_end < t_far) && hit;

            float sig = ((px * w0 + py * w1) + pz * w2) + bb;
            if (sig < 0.0f) sig = 0.0f;
            const float sstep = (valid ? sig : 0.0f) * STEP;

            vmask |= (valid ? 1u : 0u) << ((c << 2) + k);
            loc[c][k] = sum;
            sum = sum + sstep;
        }
        lsum[c] = sum;
    }

    // ---- Pass 2: four independent wave-scans (ILP overlaps shuffle latency) ----
    float run0 = lsum[0], run1 = lsum[1], run2 = lsum[2], run3 = lsum[3];
    #pragma unroll
    for (int d = 1; d < 64; d <<= 1) {
        const float y0 = __shfl_up(run0, d, 64);
        const float y1 = __shfl_up(run1, d, 64);
        const float y2 = __shfl_up(run2, d, 64);
        const float y3 = __shfl_up(run3, d, 64);
        if (lane >= d) { run0 += y0; run1 += y1; run2 += y2; run3 += y3; }
    }
    const float W0 = __shfl(run0, 63, 64);
    const float W1 = __shfl(run1, 63, 64);
    const float W2 = __shfl(run2, 63, 64);

    // chunk carries, same fp order as R15's sequential tau += W_c
    float carry[4];
    carry[0] = 0.0f;
    carry[1] = W0;
    carry[2] = W0 + W1;
    carry[3] = (W0 + W1) + W2;

    const float ex0 = carry[0] + (run0 - lsum[0]);
    const float ex1 = carry[1] + (run1 - lsum[1]);
    const float ex2 = carry[2] + (run2 - lsum[2]);
    const float ex3 = carry[3] + (run3 - lsum[3]);
    const float exbase[4] = {ex0, ex1, ex2, ex3};

    // ---- Pass 3: stores (contiguous 1KB burst per wave per output) ----
    const size_t base  = (size_t)ray * (size_t)SSTEPS;
    const float  ray_f = (float)ray;
    const float4 o0v   = make_float4(ray_f, ray_f, ray_f, ray_f);

    #pragma unroll
    for (int c = 0; c < 4; ++c) {
        const int s0 = (c << 8) + (lane << 2);
        float a1[4], a2[4], a3[4];
        #pragma unroll
        for (int k = 0; k < 4; ++k) {
            const float ts  = t_near + ((float)(s0 + k) + jit) * STEP;
            const float te  = ts + STEP;
            const bool keep = ((vmask >> ((c << 2) + k)) & 1u)
                              && ((exbase[c] + loc[c][k]) < KEEP_THR);
            a1[k] = keep ? ts : 0.0f;
            a2[k] = keep ? te : 0.0f;
            a3[k] = keep ? 1.0f : 0.0f;
        }
        const size_t o = base + (size_t)s0;
        *reinterpret_cast<float4*>(&out[o])             = o0v;
        *reinterpret_cast<float4*>(&out[NSAMP + o])     = make_float4(a1[0], a1[1], a1[2], a1[3]);
        *reinterpret_cast<float4*>(&out[2 * NSAMP + o]) = make_float4(a2[0], a2[1], a2[2], a2[3]);
        *reinterpret_cast<float4*>(&out[3 * NSAMP + o]) = make_float4(a3[0], a3[1], a3[2], a3[3]);
    }
}

extern "C" void kernel_launch(void* const* d_in, const int* in_sizes, int n_in,
                              void* d_out, int out_size, void* d_ws, size_t ws_size,
                              hipStream_t stream) {
    const float* rays_o           = (const float*)d_in[0];
    const float* rays_d           = (const float*)d_in[1];
    const float* jitter           = (const float*)d_in[2];
    const float* Wd               = (const float*)d_in[3];
    const float* bd               = (const float*)d_in[4];
    const unsigned char* binaries = (const unsigned char*)d_in[5];
    float* out                    = (float*)d_out;

    // 4 waves (4 rays) per 256-thread block; 4096 blocks = 16384 waves.
    NeRFAccSampler_55791625175295_kernel<<<NRAYS / 4, 256, 0, stream>>>(
        rays_o, rays_d, jitter, Wd, bd, binaries, out);
}